// Round 1
// baseline (7517.682 us; speedup 1.0000x reference)
//
#include <hip/hip_runtime.h>
#include <cstdint>
#include <cstddef>

typedef unsigned short u16;
typedef float f32x4 __attribute__((ext_vector_type(4)));
typedef short bf16x8 __attribute__((ext_vector_type(8)));

// Model constants
#define BB 32
#define TT 96
#define INF_ 256
#define HH 512
#define HEADS 4
#define VV 32000
#define LSTMIN 2304           // IN + HEADS*H
#define K0_ 2816              // LSTMIN + H  (gates0 K)
#define K1_ 1024              // H + H       (gates1 K)
#define KO_ 2560              // (1+HEADS)*H (output K)
#define MROWS 3072            // B*T

// ---------------- helpers ----------------
__device__ __forceinline__ u16 f2b(float f) {
  union { float f; unsigned u; } v; v.f = f;
  unsigned r = v.u + 0x7fffu + ((v.u >> 16) & 1u);
  return (u16)(r >> 16);
}
__device__ __forceinline__ float sigm(float x) { return 1.f / (1.f + __expf(-x)); }

__device__ __forceinline__ void stage16(const void* g, u16* lds_base, int lane) {
#if __has_builtin(__builtin_amdgcn_global_load_lds)
  __builtin_amdgcn_global_load_lds((__attribute__((address_space(1))) void*)(g),
                                   (__attribute__((address_space(3))) void*)(lds_base),
                                   16, 0, 0);
#else
  *(uint4*)(lds_base + (size_t)lane * 8) = *(const uint4*)g;
#endif
}

// ---------------- setup: weight reorder/convert + state zero-init ----------------
// Wr0[h*4+g][k] = concat(Wih0,Whh0)[g*512+h][k]  (bf16, K=2816)
// Wr1[h*4+g][k] = concat(Wih1,Whh1)[g*512+h][k]  (bf16, K=1024)
// Wa1r[n][k]: n<512 -> Wa1[n][k] (h1 half), n>=512 -> Wa1[n-512][512+k] (buf half)
__global__ void k_setup(const float* __restrict__ Wih0, const float* __restrict__ Whh0,
                        const float* __restrict__ bih0, const float* __restrict__ bhh0,
                        const float* __restrict__ Wih1, const float* __restrict__ Whh1,
                        const float* __restrict__ bih1, const float* __restrict__ bhh1,
                        const float* __restrict__ Wa1,
                        u16* Wr0, u16* Wr1, u16* Wa1r, float* bsum0, float* bsum1,
                        float* h1st, float* c0st, float* c1st, u16* h0h1_0, u16* h0h1_1) {
  int idx = blockIdx.x * 256 + threadIdx.x;
  if (idx < 5767168) {
    int row = idx / 2816, k = idx % 2816;
    int h = row >> 2, g = row & 3, src = g * 512 + h;
    float v = (k < 2304) ? Wih0[(size_t)src * 2304 + k] : Whh0[src * 512 + (k - 2304)];
    Wr0[idx] = f2b(v); return;
  }
  idx -= 5767168;
  if (idx < 2097152) {
    int row = idx / 1024, k = idx % 1024;
    int h = row >> 2, g = row & 3, src = g * 512 + h;
    float v = (k < 512) ? Wih1[src * 512 + k] : Whh1[src * 512 + (k - 512)];
    Wr1[idx] = f2b(v); return;
  }
  idx -= 2097152;
  if (idx < 524288) {
    int n = idx / 512, k = idx % 512;
    float v = (n < 512) ? Wa1[n * 1024 + k] : Wa1[(n - 512) * 1024 + 512 + k];
    Wa1r[idx] = f2b(v); return;
  }
  idx -= 524288;
  if (idx < 2048) { bsum0[idx] = bih0[(idx & 3) * 512 + (idx >> 2)] + bhh0[(idx & 3) * 512 + (idx >> 2)]; return; }
  idx -= 2048;
  if (idx < 2048) { bsum1[idx] = bih1[(idx & 3) * 512 + (idx >> 2)] + bhh1[(idx & 3) * 512 + (idx >> 2)]; return; }
  idx -= 2048;
  if (idx < 16384) { h1st[idx] = 0.f; return; } idx -= 16384;
  if (idx < 16384) { c0st[idx] = 0.f; return; } idx -= 16384;
  if (idx < 16384) { c1st[idx] = 0.f; return; } idx -= 16384;
  if (idx < 16384) { int b = idx >> 9, h = idx & 511; h0h1_0[b * 1024 + 512 + h] = 0; return; } idx -= 16384;
  if (idx < 16384) { int b = idx >> 9, h = idx & 511; h0h1_1[b * 1024 + h] = 0; return; }
}

// Wo fp32 -> bf16 (only if workspace large enough)
__global__ void k_wob(const float* __restrict__ Wo, u16* __restrict__ Wob) {
  size_t c = ((size_t)blockIdx.x * 256 + threadIdx.x) * 8;
  float4 f0 = *(const float4*)(Wo + c);
  float4 f1 = *(const float4*)(Wo + c + 4);
  union { bf16x8 v; u16 u[8]; } p;
  p.u[0] = f2b(f0.x); p.u[1] = f2b(f0.y); p.u[2] = f2b(f0.z); p.u[3] = f2b(f0.w);
  p.u[4] = f2b(f1.x); p.u[5] = f2b(f1.y); p.u[6] = f2b(f1.z); p.u[7] = f2b(f1.w);
  *(bf16x8*)(Wob + c) = p.v;
}

// ---------------- K0: projection GEMM  (M=32, N=1024, K=512) ----------------
// hb[b][h] = h1 . Wa1[h,0:512] + ba1[h];  bufp[b][t][h] = h1 . Wa1[h,512:1024]
__global__ __launch_bounds__(256) void k_proj(int t, const u16* __restrict__ hA,
    const u16* __restrict__ Wa1r, const float* __restrict__ ba1,
    float* __restrict__ hb_buf, float* __restrict__ bufp) {
  const int tid = threadIdx.x, lane = tid & 63, wave = tid >> 6;
  const int mt = wave & 1, nth = wave >> 1;
  const int lr = lane & 15, quad = lane >> 4;
  const int n0 = blockIdx.x * 32;
  const u16* ap = hA + (mt * 16 + lr) * 1024 + 512 + quad * 8;   // h1 part (bf16)
  const u16* bp = Wa1r + (size_t)(n0 + nth * 16 + lr) * 512 + quad * 8;
  f32x4 acc = {0.f, 0.f, 0.f, 0.f};
#pragma unroll
  for (int kk = 0; kk < 512; kk += 32)
    acc = __builtin_amdgcn_mfma_f32_16x16x32_bf16(*(const bf16x8*)(ap + kk),
                                                  *(const bf16x8*)(bp + kk), acc, 0, 0, 0);
  const int n = n0 + nth * 16 + lr;
#pragma unroll
  for (int r = 0; r < 4; ++r) {
    int b = mt * 16 + quad * 4 + r;
    float v = acc[r];
    if (n < 512) hb_buf[b * 512 + n] = v + ba1[n];
    else bufp[((size_t)b * 97 + t) * 512 + (n - 512)] = v;
  }
}

// ---------------- K1: attention scores + softmax + context ----------------
__global__ __launch_bounds__(256) void k_attn(int t,
    const float* __restrict__ inputs, const float* __restrict__ h1_state,
    const float* __restrict__ hb_buf, const float* __restrict__ bufp,
    float* __restrict__ buf, const float* __restrict__ Wa2, const float* __restrict__ ba2,
    u16* __restrict__ xcv, u16* __restrict__ Aph2) {
  const int b = blockIdx.x, tid = threadIdx.x;
  __shared__ float hbs[512];
  __shared__ float wa2s[2048];
  __shared__ float satt[97 * 4];
  __shared__ float winv[4];
  for (int d = tid; d < 512; d += 256) {
    hbs[d] = hb_buf[b * 512 + d];
    buf[((size_t)b * 97 + t) * 512 + d] = h1_state[b * 512 + d];  // slot t = h1_{t-1}
  }
  for (int d = tid; d < 2048; d += 256) wa2s[d] = Wa2[d];
  xcv[b * 2304 + tid] = f2b(inputs[((size_t)b * 96 + t) * 256 + tid]);  // x_t (256 cols)
  __syncthreads();
  // scores: 4 lanes per history slot j
  {
    const int jj = tid >> 2, part = tid & 3, off = part * 128;
    const float bz0 = ba2[0], bz1 = ba2[1], bz2 = ba2[2], bz3 = ba2[3];
    for (int j = jj; j <= t; j += 64) {
      const float* bp = bufp + ((size_t)b * 97 + j) * 512 + off;
      float s0 = 0, s1 = 0, s2 = 0, s3 = 0;
      for (int d = 0; d < 128; d += 4) {
        float4 bv = *(const float4*)(bp + d);
        float4 hv = *(const float4*)(hbs + off + d);
        float e0 = fmaxf(hv.x + bv.x, 0.f), e1 = fmaxf(hv.y + bv.y, 0.f);
        float e2 = fmaxf(hv.z + bv.z, 0.f), e3 = fmaxf(hv.w + bv.w, 0.f);
        float4 w0 = *(const float4*)(wa2s + 0 * 512 + off + d);
        float4 w1 = *(const float4*)(wa2s + 1 * 512 + off + d);
        float4 w2 = *(const float4*)(wa2s + 2 * 512 + off + d);
        float4 w3 = *(const float4*)(wa2s + 3 * 512 + off + d);
        s0 += e0 * w0.x + e1 * w0.y + e2 * w0.z + e3 * w0.w;
        s1 += e0 * w1.x + e1 * w1.y + e2 * w1.z + e3 * w1.w;
        s2 += e0 * w2.x + e1 * w2.y + e2 * w2.z + e3 * w2.w;
        s3 += e0 * w3.x + e1 * w3.y + e2 * w3.z + e3 * w3.w;
      }
      s0 += __shfl_xor(s0, 1); s0 += __shfl_xor(s0, 2);
      s1 += __shfl_xor(s1, 1); s1 += __shfl_xor(s1, 2);
      s2 += __shfl_xor(s2, 1); s2 += __shfl_xor(s2, 2);
      s3 += __shfl_xor(s3, 1); s3 += __shfl_xor(s3, 2);
      if (part == 0) {
        satt[j * 4 + 0] = fmaxf(s0 + bz0, 0.f);
        satt[j * 4 + 1] = fmaxf(s1 + bz1, 0.f);
        satt[j * 4 + 2] = fmaxf(s2 + bz2, 0.f);
        satt[j * 4 + 3] = fmaxf(s3 + bz3, 0.f);
      }
    }
  }
  __syncthreads();
  if (tid < 4) {  // masked softmax (j>t excluded by construction)
    const int k = tid;
    float m = 0.f;
    for (int j = 0; j <= t; ++j) m = fmaxf(m, satt[j * 4 + k]);
    float sum = 0.f;
    for (int j = 0; j <= t; ++j) { float e = __expf(satt[j * 4 + k] - m); satt[j * 4 + k] = e; sum += e; }
    winv[k] = 1.f / sum;
  }
  __syncthreads();
  {  // cvec[b][k][h] = sum_j att * buf ; write bf16 into xcv and A_ph2
    const int k = tid >> 6, hc = tid & 63;
    float a0 = 0, a1 = 0, a2 = 0, a3 = 0, a4 = 0, a5 = 0, a6 = 0, a7 = 0;
    const float* bbase = buf + (size_t)b * 97 * 512 + hc * 8;
    for (int j = 0; j <= t; ++j) {
      float a = satt[j * 4 + k];
      const float* bp = bbase + j * 512;
      float4 v0 = *(const float4*)(bp);
      float4 v1 = *(const float4*)(bp + 4);
      a0 += a * v0.x; a1 += a * v0.y; a2 += a * v0.z; a3 += a * v0.w;
      a4 += a * v1.x; a5 += a * v1.y; a6 += a * v1.z; a7 += a * v1.w;
    }
    const float inv = winv[k];
    union { bf16x8 v; u16 u[8]; } p;
    p.u[0] = f2b(a0 * inv); p.u[1] = f2b(a1 * inv); p.u[2] = f2b(a2 * inv); p.u[3] = f2b(a3 * inv);
    p.u[4] = f2b(a4 * inv); p.u[5] = f2b(a5 * inv); p.u[6] = f2b(a6 * inv); p.u[7] = f2b(a7 * inv);
    *(bf16x8*)(xcv + b * 2304 + 256 + k * 512 + hc * 8) = p.v;
    *(bf16x8*)(Aph2 + ((size_t)t * 32 + b) * 2560 + 512 + k * 512 + hc * 8) = p.v;
  }
}

// ---------------- K2: gates0 GEMM + cell0 (M=32,N=2048,K=2816) ----------------
__global__ __launch_bounds__(256) void k_gates0(
    const u16* __restrict__ xcv, const u16* __restrict__ hprev,
    const u16* __restrict__ Wr0, const float* __restrict__ bsum0,
    float* __restrict__ c0_state, u16* __restrict__ hcur) {
  const int tid = threadIdx.x, lane = tid & 63, wave = tid >> 6;
  const int mt = wave & 1, nth = wave >> 1;
  const int lr = lane & 15, quad = lane >> 4;
  const int n0 = blockIdx.x * 32;
  const int arow = mt * 16 + lr;
  const u16* ap = xcv + arow * 2304 + quad * 8;
  const u16* ap2 = hprev + arow * 1024 + quad * 8;   // h0_{t-1} in cols 0:512
  const u16* bp = Wr0 + (size_t)(n0 + nth * 16 + lr) * 2816 + quad * 8;
  f32x4 acc = {0.f, 0.f, 0.f, 0.f};
#pragma unroll 4
  for (int kk = 0; kk < 2304; kk += 32)
    acc = __builtin_amdgcn_mfma_f32_16x16x32_bf16(*(const bf16x8*)(ap + kk),
                                                  *(const bf16x8*)(bp + kk), acc, 0, 0, 0);
#pragma unroll 4
  for (int kk = 0; kk < 512; kk += 32)
    acc = __builtin_amdgcn_mfma_f32_16x16x32_bf16(*(const bf16x8*)(ap2 + kk),
                                                  *(const bf16x8*)(bp + 2304 + kk), acc, 0, 0, 0);
  __shared__ float g_lds[32 * 32];
  {
    float bias = bsum0[n0 + nth * 16 + lr];
#pragma unroll
    for (int r = 0; r < 4; ++r)
      g_lds[(mt * 16 + quad * 4 + r) * 32 + nth * 16 + lr] = acc[r] + bias;
  }
  __syncthreads();
  const int b = tid >> 3, hl = tid & 7;
  const int habs = (n0 >> 2) + hl;
  const float* gr = g_lds + b * 32 + hl * 4;
  float ci = sigm(gr[0]), cf = sigm(gr[1]), cg = tanhf(gr[2]), co = sigm(gr[3]);
  float c = c0_state[b * 512 + habs];
  float c2 = cf * c + ci * cg;
  float hn = co * tanhf(c2);
  c0_state[b * 512 + habs] = c2;
  hcur[b * 1024 + habs] = f2b(hn);   // h0n -> A-operand for gates1 & next-step gates0
}

// ---------------- K3: gates1 GEMM + cell1 (M=32,N=2048,K=1024) ----------------
__global__ __launch_bounds__(256) void k_gates1(int t,
    const u16* __restrict__ hA, const u16* __restrict__ Wr1, const float* __restrict__ bsum1,
    float* __restrict__ c1_state, float* __restrict__ h1_state,
    u16* __restrict__ hB, u16* __restrict__ Aph2) {
  const int tid = threadIdx.x, lane = tid & 63, wave = tid >> 6;
  const int mt = wave & 1, nth = wave >> 1;
  const int lr = lane & 15, quad = lane >> 4;
  const int n0 = blockIdx.x * 32;
  const u16* ap = hA + (mt * 16 + lr) * 1024 + quad * 8;   // [h0n | h1_{t-1}]
  const u16* bp = Wr1 + (size_t)(n0 + nth * 16 + lr) * 1024 + quad * 8;
  f32x4 acc = {0.f, 0.f, 0.f, 0.f};
#pragma unroll 4
  for (int kk = 0; kk < 1024; kk += 32)
    acc = __builtin_amdgcn_mfma_f32_16x16x32_bf16(*(const bf16x8*)(ap + kk),
                                                  *(const bf16x8*)(bp + kk), acc, 0, 0, 0);
  __shared__ float g_lds[32 * 32];
  {
    float bias = bsum1[n0 + nth * 16 + lr];
#pragma unroll
    for (int r = 0; r < 4; ++r)
      g_lds[(mt * 16 + quad * 4 + r) * 32 + nth * 16 + lr] = acc[r] + bias;
  }
  __syncthreads();
  const int b = tid >> 3, hl = tid & 7;
  const int habs = (n0 >> 2) + hl;
  const float* gr = g_lds + b * 32 + hl * 4;
  float ci = sigm(gr[0]), cf = sigm(gr[1]), cg = tanhf(gr[2]), co = sigm(gr[3]);
  float c = c1_state[b * 512 + habs];
  float c2 = cf * c + ci * cg;
  float hn = co * tanhf(c2);
  c1_state[b * 512 + habs] = c2;
  h1_state[b * 512 + habs] = hn;
  hB[b * 1024 + 512 + habs] = f2b(hn);                       // h1_t for next step (ping-pong)
  Aph2[((size_t)t * 32 + b) * 2560 + habs] = f2b(hn);        // output-head input
}

// ---------------- K4: output GEMM  (3072 x 32000 x 2560, bf16 MFMA) ----------------
template <bool PREB>
__global__ __launch_bounds__(256) void k_gemm(
    const u16* __restrict__ A, const float* __restrict__ Wo, const u16* __restrict__ Wob,
    const float* __restrict__ bo, float* __restrict__ out) {
  const int tid = threadIdx.x, lane = tid & 63, wave = tid >> 6;
  const int wm = wave >> 1, wn = wave & 1;
  const int lr = lane & 15, quad = lane >> 4;
  const int m0 = blockIdx.y * 128, n0 = blockIdx.x * 128;
  __shared__ u16 As[128 * 32];
  __shared__ u16 Bs[128 * 32];
  f32x4 acc[4][4];
#pragma unroll
  for (int i = 0; i < 4; ++i)
#pragma unroll
    for (int j = 0; j < 4; ++j) acc[i][j] = {0.f, 0.f, 0.f, 0.f};
  const int srow = lane >> 2, scol = (lane & 3) * 8;
  for (int kk = 0; kk < 2560; kk += 32) {
    __syncthreads();
    stage16(A + (size_t)(m0 + wave * 16 + srow) * 2560 + kk + scol, As + wave * 512, lane);
    stage16(A + (size_t)(m0 + (wave + 4) * 16 + srow) * 2560 + kk + scol, As + (wave + 4) * 512, lane);
    if constexpr (PREB) {
      stage16(Wob + (size_t)(n0 + wave * 16 + srow) * 2560 + kk + scol, Bs + wave * 512, lane);
      stage16(Wob + (size_t)(n0 + (wave + 4) * 16 + srow) * 2560 + kk + scol, Bs + (wave + 4) * 512, lane);
    } else {
      const int r = tid >> 1, half = tid & 1;
      const float* g = Wo + (size_t)(n0 + r) * 2560 + kk + half * 16;
      float4 f0 = ((const float4*)g)[0], f1 = ((const float4*)g)[1];
      float4 f2v = ((const float4*)g)[2], f3v = ((const float4*)g)[3];
      union { bf16x8 v; u16 u[8]; } p0, p1;
      p0.u[0] = f2b(f0.x); p0.u[1] = f2b(f0.y); p0.u[2] = f2b(f0.z); p0.u[3] = f2b(f0.w);
      p0.u[4] = f2b(f1.x); p0.u[5] = f2b(f1.y); p0.u[6] = f2b(f1.z); p0.u[7] = f2b(f1.w);
      p1.u[0] = f2b(f2v.x); p1.u[1] = f2b(f2v.y); p1.u[2] = f2b(f2v.z); p1.u[3] = f2b(f2v.w);
      p1.u[4] = f2b(f3v.x); p1.u[5] = f2b(f3v.y); p1.u[6] = f2b(f3v.z); p1.u[7] = f2b(f3v.w);
      bf16x8* d = (bf16x8*)(Bs + r * 32 + half * 16);
      d[0] = p0.v; d[1] = p1.v;
    }
    __syncthreads();
    bf16x8 af[4], bfv[4];
#pragma unroll
    for (int i = 0; i < 4; ++i) af[i] = *(const bf16x8*)(As + (wm * 64 + i * 16 + lr) * 32 + quad * 8);
#pragma unroll
    for (int j = 0; j < 4; ++j) bfv[j] = *(const bf16x8*)(Bs + (wn * 64 + j * 16 + lr) * 32 + quad * 8);
#pragma unroll
    for (int i = 0; i < 4; ++i)
#pragma unroll
      for (int j = 0; j < 4; ++j)
        acc[i][j] = __builtin_amdgcn_mfma_f32_16x16x32_bf16(af[i], bfv[j], acc[i][j], 0, 0, 0);
  }
#pragma unroll
  for (int j = 0; j < 4; ++j) {
    const int n = n0 + wn * 64 + j * 16 + lr;
    const float bias = bo[n];
#pragma unroll
    for (int i = 0; i < 4; ++i)
#pragma unroll
      for (int r = 0; r < 4; ++r) {
        int m = m0 + wm * 64 + i * 16 + quad * 4 + r;   // A-row = t*32 + b
        out[((size_t)(m & 31) * 96 + (m >> 5)) * 32000 + n] = acc[i][j][r] + bias;
      }
  }
}

// ---------------- K5: in-place log-softmax over rows of 32000 ----------------
__global__ __launch_bounds__(256) void k_lsm(float* __restrict__ out) {
  float* p = out + (size_t)blockIdx.x * 32000;
  const int tid = threadIdx.x, lane = tid & 63, wave = tid >> 6;
  __shared__ float red[8];
  float m = -3.4e38f;
  for (int i = tid * 4; i < 32000; i += 1024) {
    float4 v = *(const float4*)(p + i);
    m = fmaxf(m, fmaxf(fmaxf(v.x, v.y), fmaxf(v.z, v.w)));
  }
  for (int o = 32; o; o >>= 1) m = fmaxf(m, __shfl_xor(m, o));
  if (lane == 0) red[wave] = m;
  __syncthreads();
  m = fmaxf(fmaxf(red[0], red[1]), fmaxf(red[2], red[3]));
  float s = 0.f;
  for (int i = tid * 4; i < 32000; i += 1024) {
    float4 v = *(const float4*)(p + i);
    s += __expf(v.x - m) + __expf(v.y - m) + __expf(v.z - m) + __expf(v.w - m);
  }
  for (int o = 32; o; o >>= 1) s += __shfl_xor(s, o);
  if (lane == 0) red[4 + wave] = s;
  __syncthreads();
  s = red[4] + red[5] + red[6] + red[7];
  const float lz = m + __logf(s);
  for (int i = tid * 4; i < 32000; i += 1024) {
    float4 v = *(const float4*)(p + i);
    v.x -= lz; v.y -= lz; v.z -= lz; v.w -= lz;
    *(float4*)(p + i) = v;
  }
}

// ---------------- host ----------------
extern "C" void kernel_launch(void* const* d_in, const int* in_sizes, int n_in,
                              void* d_out, int out_size, void* d_ws, size_t ws_size,
                              hipStream_t stream) {
  const float* inputs = (const float*)d_in[0];
  const float* Wih0 = (const float*)d_in[1];
  const float* Whh0 = (const float*)d_in[2];
  const float* bih0 = (const float*)d_in[3];
  const float* bhh0 = (const float*)d_in[4];
  const float* Wih1 = (const float*)d_in[5];
  const float* Whh1 = (const float*)d_in[6];
  const float* bih1 = (const float*)d_in[7];
  const float* bhh1 = (const float*)d_in[8];
  const float* Wa1 = (const float*)d_in[9];
  const float* ba1 = (const float*)d_in[10];
  const float* Wa2 = (const float*)d_in[11];
  const float* ba2 = (const float*)d_in[12];
  const float* Wo = (const float*)d_in[13];
  const float* bo = (const float*)d_in[14];

  char* w = (char*)d_ws;
  u16* Wr0    = (u16*)(w + 0);
  u16* Wr1    = (u16*)(w + 11534336);
  u16* Wa1r   = (u16*)(w + 15728640);
  u16* Aph2   = (u16*)(w + 16777216);
  float* buf  = (float*)(w + 32505856);
  float* bufp = (float*)(w + 38862848);
  u16* xcv    = (u16*)(w + 45219840);
  u16* h0h1_0 = (u16*)(w + 45367296);
  u16* h0h1_1 = (u16*)(w + 45432832);
  float* h1st = (float*)(w + 45498368);
  float* c0st = (float*)(w + 45563904);
  float* c1st = (float*)(w + 45629440);
  float* hbb  = (float*)(w + 45694976);
  float* bsum0 = (float*)(w + 45760512);
  float* bsum1 = (float*)(w + 45768704);
  u16* Wob    = (u16*)(w + 45776896);
  const bool preb = ws_size >= (size_t)45776896 + 163840000ull;

  k_setup<<<33104, 256, 0, stream>>>(Wih0, Whh0, bih0, bhh0, Wih1, Whh1, bih1, bhh1, Wa1,
                                     Wr0, Wr1, Wa1r, bsum0, bsum1, h1st, c0st, c1st, h0h1_0, h0h1_1);
  if (preb) k_wob<<<40000, 256, 0, stream>>>(Wo, Wob);

  for (int t = 0; t < 96; ++t) {
    u16* hA = (t & 1) ? h0h1_1 : h0h1_0;   // holds [h0n_t | h1_{t-1}] during step t
    u16* hB = (t & 1) ? h0h1_0 : h0h1_1;   // holds [h0n_{t-1} | h1_t(out)]
    k_proj<<<32, 256, 0, stream>>>(t, hA, Wa1r, ba1, hbb, bufp);
    k_attn<<<32, 256, 0, stream>>>(t, inputs, h1st, hbb, bufp, buf, Wa2, ba2, xcv, Aph2);
    k_gates0<<<64, 256, 0, stream>>>(xcv, hB, Wr0, bsum0, c0st, hA);
    k_gates1<<<64, 256, 0, stream>>>(t, hA, Wr1, bsum1, c1st, h1st, hB, Aph2);
  }

  if (preb) k_gemm<true><<<dim3(250, 24), 256, 0, stream>>>(Aph2, Wo, Wob, bo, (float*)d_out);
  else      k_gemm<false><<<dim3(250, 24), 256, 0, stream>>>(Aph2, Wo, Wob, bo, (float*)d_out);
  k_lsm<<<3072, 256, 0, stream>>>((float*)d_out);
}